// Round 1
// baseline (4400.560 us; speedup 1.0000x reference)
//
#include <hip/hip_runtime.h>

#define NB 4
#define NN 8192
#define NS 2048
#define NK 32
#define NCF 64
#define R2 0.04f

// ws layout in float units
#define WS_FPSIDX 0              // int[NB*NS]      = 8192
#define WS_SQX    8192           // float[NB*NN]    = 32768
#define WS_GIDX   40960          // int[NB*NS*NK]   = 262144
#define WS_WT0    303104         // 67*64
#define WS_BB0    307392         // 64
#define WS_WT1    307456         // 64*64
#define WS_BB1    311552         // 64
#define WS_WT2    311616         // 64*128
#define WS_BB2    319808         // 128

// ---------------------------------------------------------------------------
// FPS: one block per batch, 1024 threads, 8 points/thread in registers.
// Exact semantics: dist init 1e10f, far0=0, d = ((dx*dx+dy*dy)+dz*dz) with
// NO fma contraction; dist=min(dist,d); argmax with first-index tiebreak.
// One barrier/iter via parity double-buffered per-wave maxima.
// ---------------------------------------------------------------------------
__global__ __launch_bounds__(1024)
void fps_kernel(const float* __restrict__ xyz, int* __restrict__ fps_idx,
                float* __restrict__ new_xyz)
{
#pragma clang fp contract(off)
  const int b = blockIdx.x;
  const int tid = threadIdx.x;
  const float* __restrict__ P = xyz + (size_t)b * (NN * 3);
  float px[8], py[8], pz[8], dist[8];
#pragma unroll
  for (int j = 0; j < 8; ++j) {
    int p = tid + j * 1024;
    px[j] = P[p * 3 + 0];
    py[j] = P[p * 3 + 1];
    pz[j] = P[p * 3 + 2];
    dist[j] = 1e10f;
  }
  __shared__ float sv[2][16];
  __shared__ int si[2][16];
  const int lane = tid & 63;
  const int wid = tid >> 6;
  int far = 0;
  for (int k = 0; k < NS; ++k) {
    far = __builtin_amdgcn_readfirstlane(far);
    float cx = P[far * 3 + 0], cy = P[far * 3 + 1], cz = P[far * 3 + 2];
    if (tid == 0) {
      fps_idx[b * NS + k] = far;
      float* o = new_xyz + ((size_t)b * NS + k) * 3;
      o[0] = cx; o[1] = cy; o[2] = cz;
    }
    if (k == NS - 1) break;
    float bv = -1.0f;
    int bi = 0x7fffffff;
#pragma unroll
    for (int j = 0; j < 8; ++j) {
      float dx = px[j] - cx;
      float dy = py[j] - cy;
      float dz = pz[j] - cz;
      float d = (dx * dx + dy * dy) + dz * dz;   // plain mul/add, l-to-r
      float nd = fminf(dist[j], d);
      dist[j] = nd;
      if (nd > bv) { bv = nd; bi = tid + j * 1024; }  // ascending idx -> strict >
    }
    // wave argmax (first-index tiebreak)
#pragma unroll
    for (int off = 32; off >= 1; off >>= 1) {
      float nv = __shfl_xor(bv, off);
      int ni = __shfl_xor(bi, off);
      if (nv > bv || (nv == bv && ni < bi)) { bv = nv; bi = ni; }
    }
    if (lane == 0) { sv[k & 1][wid] = bv; si[k & 1][wid] = bi; }
    __syncthreads();
    float rv = (lane < 16) ? sv[k & 1][lane] : -1.0f;
    int ri = (lane < 16) ? si[k & 1][lane] : 0x7fffffff;
#pragma unroll
    for (int off = 8; off >= 1; off >>= 1) {
      float nv = __shfl_xor(rv, off);
      int ni = __shfl_xor(ri, off);
      if (nv > rv || (nv == rv && ni < ri)) { rv = nv; ri = ni; }
    }
    far = __shfl(ri, 0);
  }
}

// ---------------------------------------------------------------------------
// sq_x = (x*x + y*y) + z*z, plain ops (matches jnp.sum(xyz**2,-1) reduce order)
// ---------------------------------------------------------------------------
__global__ void prep_sqx(const float* __restrict__ xyz, float* __restrict__ sqx)
{
#pragma clang fp contract(off)
  int t = blockIdx.x * 256 + threadIdx.x;
  if (t < NB * NN) {
    float x = xyz[t * 3 + 0], y = xyz[t * 3 + 1], z = xyz[t * 3 + 2];
    sqx[t] = (x * x + y * y) + z * z;
  }
}

// ---------------------------------------------------------------------------
// Fold BN into weights, transpose to (c,o), remap layer0 channels so that
// c'=0..63 are features (orig 3..66) and c'=64..66 are rel-xyz (orig 0..2).
// ---------------------------------------------------------------------------
__global__ void prep_w(
    const float* __restrict__ w0, const float* __restrict__ b0,
    const float* __restrict__ g0, const float* __restrict__ be0,
    const float* __restrict__ m0, const float* __restrict__ v0,
    const float* __restrict__ w1, const float* __restrict__ b1,
    const float* __restrict__ g1, const float* __restrict__ be1,
    const float* __restrict__ m1, const float* __restrict__ v1,
    const float* __restrict__ w2, const float* __restrict__ b2,
    const float* __restrict__ g2, const float* __restrict__ be2,
    const float* __restrict__ m2, const float* __restrict__ v2,
    float* __restrict__ wT0, float* __restrict__ bb0,
    float* __restrict__ wT1, float* __restrict__ bb1,
    float* __restrict__ wT2, float* __restrict__ bb2)
{
  int t = blockIdx.x * 256 + threadIdx.x;
  if (t < 4288) {
    int c = t >> 6, o = t & 63;
    int oc = (c < 64) ? (c + 3) : (c - 64);
    float sc = g0[o] * rsqrtf(v0[o] + 1e-5f);
    wT0[t] = w0[o * 67 + oc] * sc;
  } else if (t < 4352) {
    int o = t - 4288;
    float sc = g0[o] * rsqrtf(v0[o] + 1e-5f);
    bb0[o] = (b0[o] - m0[o]) * sc + be0[o];
  } else if (t < 8448) {
    int u = t - 4352;
    int c = u >> 6, o = u & 63;
    float sc = g1[o] * rsqrtf(v1[o] + 1e-5f);
    wT1[u] = w1[o * 64 + c] * sc;
  } else if (t < 8512) {
    int o = t - 8448;
    float sc = g1[o] * rsqrtf(v1[o] + 1e-5f);
    bb1[o] = (b1[o] - m1[o]) * sc + be1[o];
  } else if (t < 16704) {
    int u = t - 8512;
    int c = u >> 7, o = u & 127;
    float sc = g2[o] * rsqrtf(v2[o] + 1e-5f);
    wT2[u] = w2[o * 64 + c] * sc;
  } else if (t < 16832) {
    int o = t - 16704;
    float sc = g2[o] * rsqrtf(v2[o] + 1e-5f);
    bb2[o] = (b2[o] - m2[o]) * sc + be2[o];
  }
}

// ---------------------------------------------------------------------------
// Ball query: one wave per query point. sqr = (sq_q + sq_x) - 2*dot with
// dot as Eigen-style fma chain over (x,y,z). First 32 in-ball indices in
// ascending order; pad with the first hit (center itself always in-ball).
// ---------------------------------------------------------------------------
__global__ __launch_bounds__(256)
void ballq_kernel(const float* __restrict__ xyz, const float* __restrict__ sqx,
                  const int* __restrict__ fps_idx, int* __restrict__ gidx)
{
#pragma clang fp contract(off)
  const int lane = threadIdx.x & 63;
  const int q = blockIdx.x * 4 + (threadIdx.x >> 6);
  const int b = q >> 11;
  const int s = q & 2047;
  const float* __restrict__ P = xyz + (size_t)b * (NN * 3);
  const float* __restrict__ SQ = sqx + b * NN;
  const int cidx = fps_idx[b * NS + s];
  const float cx = P[cidx * 3 + 0], cy = P[cidx * 3 + 1], cz = P[cidx * 3 + 2];
  const float csq = SQ[cidx];
  int* __restrict__ g = gidx + (size_t)q * NK;
  int cnt = 0, firstn = 0;
  bool havefirst = false;
  for (int n0 = 0; n0 < NN; n0 += 64) {
    int n = n0 + lane;
    float x = P[n * 3 + 0], y = P[n * 3 + 1], z = P[n * 3 + 2];
    float dot = x * cx;            // first gebp step: fma(a0,b0,0) == rn(a0*b0)
    dot = fmaf(y, cy, dot);
    dot = fmaf(z, cz, dot);
    float sqr = (csq + SQ[n]) - 2.0f * dot;
    bool in_ = (sqr <= R2);
    unsigned long long m = __ballot(in_);
    if (!havefirst && m) { firstn = n0 + __builtin_ctzll(m); havefirst = true; }
    int pos = cnt + __popcll(m & ((1ull << lane) - 1ull));
    if (in_ && pos < NK) g[pos] = n;
    cnt += __popcll(m);
    if (cnt >= NK) break;
  }
  if (cnt < NK && lane < NK - cnt) g[cnt + lane] = firstn;
}

// ---------------------------------------------------------------------------
// Grouped MLP + k-max: one block (256 thr) per query. g staged in LDS,
// weights (BN-folded, (c,o) layout) from global (L2-hot). ReLU of layer 3
// deferred past the max (relu∘max == max∘relu).
// ---------------------------------------------------------------------------
__global__ __launch_bounds__(256)
void mlp_kernel(const float* __restrict__ xyz, const float* __restrict__ feat,
                const int* __restrict__ gidx, const float* __restrict__ nxyz,
                const float* __restrict__ wT0, const float* __restrict__ bb0,
                const float* __restrict__ wT1, const float* __restrict__ bb1,
                const float* __restrict__ wT2, const float* __restrict__ bb2,
                float* __restrict__ out)
{
  const int q = blockIdx.x;
  const int b = q >> 11;
  const int tid = threadIdx.x;
  __shared__ int sg[32];
  __shared__ float A[32 * 76];    // stride 76: conflict-free k-spread
  __shared__ float Bf[32 * 76];
  __shared__ float Cf[32 * 132];
  if (tid < 32) sg[tid] = gidx[(size_t)q * NK + tid];
  __syncthreads();
  const int k = tid >> 3, j = tid & 7;
  {
    const int p = sg[k];
    const float* fp = feat + ((size_t)b * NN + p) * NCF + j * 8;
    float4 f0 = *(const float4*)fp;
    float4 f1 = *(const float4*)(fp + 4);
    float* a = &A[k * 76 + j * 8];
    *(float4*)a = f0;
    *(float4*)(a + 4) = f1;
    if (j == 0) {
      float cx = nxyz[(size_t)q * 3 + 0];
      float cy = nxyz[(size_t)q * 3 + 1];
      float cz = nxyz[(size_t)q * 3 + 2];
      const float* pp = xyz + ((size_t)b * NN + p) * 3;
      A[k * 76 + 64] = pp[0] - cx;
      A[k * 76 + 65] = pp[1] - cy;
      A[k * 76 + 66] = pp[2] - cz;
    }
  }
  __syncthreads();
  const int o0 = j * 8;
  // ---- layer 1: A[k][0..66] -> Bf[k][0..63]
  {
    float4 a0 = *(const float4*)(bb0 + o0);
    float4 a1 = *(const float4*)(bb0 + o0 + 4);
    const float* Ak = &A[k * 76];
    for (int c = 0; c < 67; ++c) {
      float gv = Ak[c];
      const float* wr = wT0 + c * 64 + o0;
      float4 wa = *(const float4*)wr;
      float4 wb = *(const float4*)(wr + 4);
      a0.x = fmaf(gv, wa.x, a0.x); a0.y = fmaf(gv, wa.y, a0.y);
      a0.z = fmaf(gv, wa.z, a0.z); a0.w = fmaf(gv, wa.w, a0.w);
      a1.x = fmaf(gv, wb.x, a1.x); a1.y = fmaf(gv, wb.y, a1.y);
      a1.z = fmaf(gv, wb.z, a1.z); a1.w = fmaf(gv, wb.w, a1.w);
    }
    float* o = &Bf[k * 76 + o0];
    o[0] = fmaxf(a0.x, 0.f); o[1] = fmaxf(a0.y, 0.f);
    o[2] = fmaxf(a0.z, 0.f); o[3] = fmaxf(a0.w, 0.f);
    o[4] = fmaxf(a1.x, 0.f); o[5] = fmaxf(a1.y, 0.f);
    o[6] = fmaxf(a1.z, 0.f); o[7] = fmaxf(a1.w, 0.f);
  }
  __syncthreads();
  // ---- layer 2: Bf[k][0..63] -> A[k][0..63]
  {
    float4 a0 = *(const float4*)(bb1 + o0);
    float4 a1 = *(const float4*)(bb1 + o0 + 4);
    const float* Bk = &Bf[k * 76];
    for (int c = 0; c < 64; ++c) {
      float gv = Bk[c];
      const float* wr = wT1 + c * 64 + o0;
      float4 wa = *(const float4*)wr;
      float4 wb = *(const float4*)(wr + 4);
      a0.x = fmaf(gv, wa.x, a0.x); a0.y = fmaf(gv, wa.y, a0.y);
      a0.z = fmaf(gv, wa.z, a0.z); a0.w = fmaf(gv, wa.w, a0.w);
      a1.x = fmaf(gv, wb.x, a1.x); a1.y = fmaf(gv, wb.y, a1.y);
      a1.z = fmaf(gv, wb.z, a1.z); a1.w = fmaf(gv, wb.w, a1.w);
    }
    float* o = &A[k * 76 + o0];
    o[0] = fmaxf(a0.x, 0.f); o[1] = fmaxf(a0.y, 0.f);
    o[2] = fmaxf(a0.z, 0.f); o[3] = fmaxf(a0.w, 0.f);
    o[4] = fmaxf(a1.x, 0.f); o[5] = fmaxf(a1.y, 0.f);
    o[6] = fmaxf(a1.z, 0.f); o[7] = fmaxf(a1.w, 0.f);
  }
  __syncthreads();
  // ---- layer 3: A[k][0..63] -> Cf[k][0..127]  (no relu; folded into max)
  {
    const int t0 = j * 16;
    float4 a0 = *(const float4*)(bb2 + t0);
    float4 a1 = *(const float4*)(bb2 + t0 + 4);
    float4 a2 = *(const float4*)(bb2 + t0 + 8);
    float4 a3 = *(const float4*)(bb2 + t0 + 12);
    const float* Ak = &A[k * 76];
    for (int c = 0; c < 64; ++c) {
      float gv = Ak[c];
      const float* wr = wT2 + c * 128 + t0;
      float4 w0v = *(const float4*)wr;
      float4 w1v = *(const float4*)(wr + 4);
      float4 w2v = *(const float4*)(wr + 8);
      float4 w3v = *(const float4*)(wr + 12);
      a0.x = fmaf(gv, w0v.x, a0.x); a0.y = fmaf(gv, w0v.y, a0.y);
      a0.z = fmaf(gv, w0v.z, a0.z); a0.w = fmaf(gv, w0v.w, a0.w);
      a1.x = fmaf(gv, w1v.x, a1.x); a1.y = fmaf(gv, w1v.y, a1.y);
      a1.z = fmaf(gv, w1v.z, a1.z); a1.w = fmaf(gv, w1v.w, a1.w);
      a2.x = fmaf(gv, w2v.x, a2.x); a2.y = fmaf(gv, w2v.y, a2.y);
      a2.z = fmaf(gv, w2v.z, a2.z); a2.w = fmaf(gv, w2v.w, a2.w);
      a3.x = fmaf(gv, w3v.x, a3.x); a3.y = fmaf(gv, w3v.y, a3.y);
      a3.z = fmaf(gv, w3v.z, a3.z); a3.w = fmaf(gv, w3v.w, a3.w);
    }
    float* o = &Cf[k * 132 + t0];
    *(float4*)(o + 0) = a0;
    *(float4*)(o + 4) = a1;
    *(float4*)(o + 8) = a2;
    *(float4*)(o + 12) = a3;
  }
  __syncthreads();
  // ---- max over k, relu, store
  if (tid < 128) {
    float m = Cf[tid];
    for (int kk = 1; kk < 32; ++kk) m = fmaxf(m, Cf[kk * 132 + tid]);
    out[(size_t)(NB * NS * 3) + (size_t)q * 128 + tid] = fmaxf(m, 0.0f);
  }
}

extern "C" void kernel_launch(void* const* d_in, const int* in_sizes, int n_in,
                              void* d_out, int out_size, void* d_ws, size_t ws_size,
                              hipStream_t stream)
{
  (void)in_sizes; (void)n_in; (void)out_size; (void)ws_size;
  const float* xyz  = (const float*)d_in[0];
  const float* feat = (const float*)d_in[1];
  const float* w0 = (const float*)d_in[2];
  const float* b0 = (const float*)d_in[3];
  const float* g0 = (const float*)d_in[4];
  const float* be0 = (const float*)d_in[5];
  const float* m0 = (const float*)d_in[6];
  const float* v0 = (const float*)d_in[7];
  const float* w1 = (const float*)d_in[8];
  const float* b1 = (const float*)d_in[9];
  const float* g1 = (const float*)d_in[10];
  const float* be1 = (const float*)d_in[11];
  const float* m1 = (const float*)d_in[12];
  const float* v1 = (const float*)d_in[13];
  const float* w2 = (const float*)d_in[14];
  const float* b2 = (const float*)d_in[15];
  const float* g2 = (const float*)d_in[16];
  const float* be2 = (const float*)d_in[17];
  const float* m2 = (const float*)d_in[18];
  const float* v2 = (const float*)d_in[19];

  float* ws = (float*)d_ws;
  int* fpsi = (int*)(ws + WS_FPSIDX);
  float* sqx = ws + WS_SQX;
  int* gidx = (int*)(ws + WS_GIDX);
  float* wT0 = ws + WS_WT0; float* bb0 = ws + WS_BB0;
  float* wT1 = ws + WS_WT1; float* bb1 = ws + WS_BB1;
  float* wT2 = ws + WS_WT2; float* bb2 = ws + WS_BB2;
  float* nxyz = (float*)d_out;

  hipLaunchKernelGGL(prep_sqx, dim3((NB * NN + 255) / 256), dim3(256), 0, stream,
                     xyz, sqx);
  hipLaunchKernelGGL(prep_w, dim3(66), dim3(256), 0, stream,
                     w0, b0, g0, be0, m0, v0,
                     w1, b1, g1, be1, m1, v1,
                     w2, b2, g2, be2, m2, v2,
                     wT0, bb0, wT1, bb1, wT2, bb2);
  hipLaunchKernelGGL(fps_kernel, dim3(NB), dim3(1024), 0, stream,
                     xyz, fpsi, nxyz);
  hipLaunchKernelGGL(ballq_kernel, dim3(NB * NS / 4), dim3(256), 0, stream,
                     xyz, sqx, fpsi, gidx);
  hipLaunchKernelGGL(mlp_kernel, dim3(NB * NS), dim3(256), 0, stream,
                     xyz, feat, gidx, nxyz,
                     wT0, bb0, wT1, bb1, wT2, bb2, (float*)d_out);
}

// Round 3
// 3413.245 us; speedup vs baseline: 1.2893x; 1.2893x over previous
//
#include <hip/hip_runtime.h>

#define NB 4
#define NN 8192
#define NS 2048
#define NK 32
#define NCF 64
#define R2 0.04f

// ws layout in float units
#define WS_FPSIDX 0              // int[NB*NS]      = 8192
#define WS_SQX    8192           // float[NB*NN]    = 32768
#define WS_GIDX   40960          // int[NB*NS*NK]   = 262144
#define WS_WT0    303104         // 67*64
#define WS_BB0    307392         // 64
#define WS_WT1    307456         // 64*64
#define WS_BB1    311552         // 64
#define WS_WT2    311616         // 64*128
#define WS_BB2    319808         // 128

template <int CTRL>
__device__ __forceinline__ float dpp_fmax(float x) {
  // bound_ctrl=true: invalid lanes contribute 0.0f; all dist values >= 0 so harmless.
  int t = __builtin_amdgcn_update_dpp(0, __float_as_int(x), CTRL, 0xf, 0xf, true);
  return fmaxf(x, __int_as_float(t));
}

// ---------------------------------------------------------------------------
// FPS: one block per batch, 1024 threads, 8 points/thread in registers.
// Exact semantics preserved: dist init 1e10f, far0=0,
// d = ((dx*dx+dy*dy)+dz*dz) with NO fma contraction; dist=min(dist,d);
// argmax with first-index tiebreak.
// Reduction: per-thread fmax tree -> 6-step DPP wave max -> 8 ballots for
// index recovery (first-index exact) -> one LDS u64 atomicMax across waves.
// Center coords travel through LDS (readlane + per-wave slot), no global
// loads inside the loop. One barrier per iteration.
// ---------------------------------------------------------------------------
__global__ __launch_bounds__(1024)
void fps_kernel(const float* __restrict__ xyz, int* __restrict__ fps_idx,
                float* __restrict__ new_xyz)
{
#pragma clang fp contract(off)
  const int b = blockIdx.x;
  const int tid = threadIdx.x;
  const int lane = tid & 63;
  const int wid = tid >> 6;
  const float* __restrict__ P = xyz + (size_t)b * (NN * 3);

  __shared__ unsigned long long sred[3];   // triple-buffered reduce slot
  __shared__ float wslot[2][16][4];        // double-buffered per-wave winner coords

  float px[8], py[8], pz[8], dist[8];
#pragma unroll
  for (int j = 0; j < 8; ++j) {
    int p = tid + j * 1024;
    px[j] = P[p * 3 + 0];
    py[j] = P[p * 3 + 1];
    pz[j] = P[p * 3 + 2];
    dist[j] = 1e10f;
  }
  if (tid == 0) { sred[0] = 0ull; sred[1] = 0ull; sred[2] = 0ull; }
  float cx = P[0], cy = P[1], cz = P[2];   // first center = point 0
  int far = 0;
  __syncthreads();

  for (int k = 0; k < NS; ++k) {
    if (tid == 0) {
      fps_idx[b * NS + k] = far;
      float* o = new_xyz + ((size_t)b * NS + k) * 3;
      o[0] = cx; o[1] = cy; o[2] = cz;
    }
    if (k == NS - 1) break;

    // ---- distance update + thread max (exact math, no index tracking)
    float bv = -1.0f;
#pragma unroll
    for (int j = 0; j < 8; ++j) {
      float dx = px[j] - cx;
      float dy = py[j] - cy;
      float dz = pz[j] - cz;
      float d = (dx * dx + dy * dy) + dz * dz;   // plain mul/add, l-to-r
      float nd = fminf(dist[j], d);
      dist[j] = nd;
      bv = fmaxf(bv, nd);
    }
    // ---- wave max via DPP ladder (result in lane 63)
    bv = dpp_fmax<0x111>(bv);  // row_shr:1
    bv = dpp_fmax<0x112>(bv);  // row_shr:2
    bv = dpp_fmax<0x114>(bv);  // row_shr:4
    bv = dpp_fmax<0x118>(bv);  // row_shr:8
    bv = dpp_fmax<0x142>(bv);  // row_bcast:15
    bv = dpp_fmax<0x143>(bv);  // row_bcast:31
    unsigned wmaxbits = (unsigned)__builtin_amdgcn_readlane(__float_as_int(bv), 63);
    float wmax = __uint_as_float(wmaxbits);

    // ---- index recovery: global idx = tid + j*1024 -> lexicographic (j, lane)
    int jwin = 0;
    unsigned long long mwin = 0ull;
#pragma unroll
    for (int j = 7; j >= 0; --j) {
      unsigned long long mj = __ballot(dist[j] == wmax);
      if (mj) { jwin = j; mwin = mj; }   // uniform select
    }
    int lanewin = (int)__builtin_ctzll(mwin);
    int widx = wid * 64 + lanewin + jwin * 1024;

    // ---- pull winner coords out of lane `lanewin` (uniform branch on jwin)
    float wxb = 0.f, wyb = 0.f, wzb = 0.f;
#pragma unroll
    for (int j = 0; j < 8; ++j) {
      if (jwin == j) {
        wxb = __int_as_float(__builtin_amdgcn_readlane(__float_as_int(px[j]), lanewin));
        wyb = __int_as_float(__builtin_amdgcn_readlane(__float_as_int(py[j]), lanewin));
        wzb = __int_as_float(__builtin_amdgcn_readlane(__float_as_int(pz[j]), lanewin));
      }
    }
    const int ws = k & 1;
    if (lane == 0) {
      wslot[ws][wid][0] = wxb;
      wslot[ws][wid][1] = wyb;
      wslot[ws][wid][2] = wzb;
      unsigned long long key =
          ((unsigned long long)wmaxbits << 32) | (0xFFFFFFFFu - (unsigned)widx);
      atomicMax(&sred[k % 3], key);
    }
    if (tid == 0) sred[(k + 1) % 3] = 0ull;   // reset next slot (pre-barrier: race-free)
    __syncthreads();

    unsigned long long kk = sred[k % 3];
    far = (int)(0xFFFFFFFFu - (unsigned)kk);
    int ww = (far & 1023) >> 6;
    cx = wslot[ws][ww][0];
    cy = wslot[ws][ww][1];
    cz = wslot[ws][ww][2];
  }
}

// ---------------------------------------------------------------------------
// sq_x = (x*x + y*y) + z*z, plain ops (matches jnp.sum(xyz**2,-1) reduce order)
// ---------------------------------------------------------------------------
__global__ void prep_sqx(const float* __restrict__ xyz, float* __restrict__ sqx)
{
#pragma clang fp contract(off)
  int t = blockIdx.x * 256 + threadIdx.x;
  if (t < NB * NN) {
    float x = xyz[t * 3 + 0], y = xyz[t * 3 + 1], z = xyz[t * 3 + 2];
    sqx[t] = (x * x + y * y) + z * z;
  }
}

// ---------------------------------------------------------------------------
// Fold BN into weights, transpose to (c,o), remap layer0 channels so that
// c'=0..63 are features (orig 3..66) and c'=64..66 are rel-xyz (orig 0..2).
// ---------------------------------------------------------------------------
__global__ void prep_w(
    const float* __restrict__ w0, const float* __restrict__ b0,
    const float* __restrict__ g0, const float* __restrict__ be0,
    const float* __restrict__ m0, const float* __restrict__ v0,
    const float* __restrict__ w1, const float* __restrict__ b1,
    const float* __restrict__ g1, const float* __restrict__ be1,
    const float* __restrict__ m1, const float* __restrict__ v1,
    const float* __restrict__ w2, const float* __restrict__ b2,
    const float* __restrict__ g2, const float* __restrict__ be2,
    const float* __restrict__ m2, const float* __restrict__ v2,
    float* __restrict__ wT0, float* __restrict__ bb0,
    float* __restrict__ wT1, float* __restrict__ bb1,
    float* __restrict__ wT2, float* __restrict__ bb2)
{
  int t = blockIdx.x * 256 + threadIdx.x;
  if (t < 4288) {
    int c = t >> 6, o = t & 63;
    int oc = (c < 64) ? (c + 3) : (c - 64);
    float sc = g0[o] * rsqrtf(v0[o] + 1e-5f);
    wT0[t] = w0[o * 67 + oc] * sc;
  } else if (t < 4352) {
    int o = t - 4288;
    float sc = g0[o] * rsqrtf(v0[o] + 1e-5f);
    bb0[o] = (b0[o] - m0[o]) * sc + be0[o];
  } else if (t < 8448) {
    int u = t - 4352;
    int c = u >> 6, o = u & 63;
    float sc = g1[o] * rsqrtf(v1[o] + 1e-5f);
    wT1[u] = w1[o * 64 + c] * sc;
  } else if (t < 8512) {
    int o = t - 8448;
    float sc = g1[o] * rsqrtf(v1[o] + 1e-5f);
    bb1[o] = (b1[o] - m1[o]) * sc + be1[o];
  } else if (t < 16704) {
    int u = t - 8512;
    int c = u >> 7, o = u & 127;
    float sc = g2[o] * rsqrtf(v2[o] + 1e-5f);
    wT2[u] = w2[o * 64 + c] * sc;
  } else if (t < 16832) {
    int o = t - 16704;
    float sc = g2[o] * rsqrtf(v2[o] + 1e-5f);
    bb2[o] = (b2[o] - m2[o]) * sc + be2[o];
  }
}

// ---------------------------------------------------------------------------
// Ball query: one wave per query point. sqr = (sq_q + sq_x) - 2*dot with
// dot as Eigen-style fma chain over (x,y,z). First 32 in-ball indices in
// ascending order; pad with the first hit (center itself always in-ball).
// ---------------------------------------------------------------------------
__global__ __launch_bounds__(256)
void ballq_kernel(const float* __restrict__ xyz, const float* __restrict__ sqx,
                  const int* __restrict__ fps_idx, int* __restrict__ gidx)
{
#pragma clang fp contract(off)
  const int lane = threadIdx.x & 63;
  const int q = blockIdx.x * 4 + (threadIdx.x >> 6);
  const int b = q >> 11;
  const int s = q & 2047;
  const float* __restrict__ P = xyz + (size_t)b * (NN * 3);
  const float* __restrict__ SQ = sqx + b * NN;
  const int cidx = fps_idx[b * NS + s];
  const float cx = P[cidx * 3 + 0], cy = P[cidx * 3 + 1], cz = P[cidx * 3 + 2];
  const float csq = SQ[cidx];
  int* __restrict__ g = gidx + (size_t)q * NK;
  int cnt = 0, firstn = 0;
  bool havefirst = false;
  for (int n0 = 0; n0 < NN; n0 += 64) {
    int n = n0 + lane;
    float x = P[n * 3 + 0], y = P[n * 3 + 1], z = P[n * 3 + 2];
    float dot = x * cx;            // first gebp step: fma(a0,b0,0) == rn(a0*b0)
    dot = fmaf(y, cy, dot);
    dot = fmaf(z, cz, dot);
    float sqr = (csq + SQ[n]) - 2.0f * dot;
    bool in_ = (sqr <= R2);
    unsigned long long m = __ballot(in_);
    if (!havefirst && m) { firstn = n0 + __builtin_ctzll(m); havefirst = true; }
    int pos = cnt + __popcll(m & ((1ull << lane) - 1ull));
    if (in_ && pos < NK) g[pos] = n;
    cnt += __popcll(m);
    if (cnt >= NK) break;
  }
  if (cnt < NK && lane < NK - cnt) g[cnt + lane] = firstn;
}

// ---------------------------------------------------------------------------
// Grouped MLP + k-max: one block (256 thr) per query. g staged in LDS,
// weights (BN-folded, (c,o) layout) from global (L2-hot). ReLU of layer 3
// deferred past the max (relu∘max == max∘relu).
// ---------------------------------------------------------------------------
__global__ __launch_bounds__(256)
void mlp_kernel(const float* __restrict__ xyz, const float* __restrict__ feat,
                const int* __restrict__ gidx, const float* __restrict__ nxyz,
                const float* __restrict__ wT0, const float* __restrict__ bb0,
                const float* __restrict__ wT1, const float* __restrict__ bb1,
                const float* __restrict__ wT2, const float* __restrict__ bb2,
                float* __restrict__ out)
{
  const int q = blockIdx.x;
  const int b = q >> 11;
  const int tid = threadIdx.x;
  __shared__ int sg[32];
  __shared__ float A[32 * 76];    // stride 76: conflict-free k-spread
  __shared__ float Bf[32 * 76];
  __shared__ float Cf[32 * 132];
  if (tid < 32) sg[tid] = gidx[(size_t)q * NK + tid];
  __syncthreads();
  const int k = tid >> 3, j = tid & 7;
  {
    const int p = sg[k];
    const float* fp = feat + ((size_t)b * NN + p) * NCF + j * 8;
    float4 f0 = *(const float4*)fp;
    float4 f1 = *(const float4*)(fp + 4);
    float* a = &A[k * 76 + j * 8];
    *(float4*)a = f0;
    *(float4*)(a + 4) = f1;
    if (j == 0) {
      float cx = nxyz[(size_t)q * 3 + 0];
      float cy = nxyz[(size_t)q * 3 + 1];
      float cz = nxyz[(size_t)q * 3 + 2];
      const float* pp = xyz + ((size_t)b * NN + p) * 3;
      A[k * 76 + 64] = pp[0] - cx;
      A[k * 76 + 65] = pp[1] - cy;
      A[k * 76 + 66] = pp[2] - cz;
    }
  }
  __syncthreads();
  const int o0 = j * 8;
  // ---- layer 1: A[k][0..66] -> Bf[k][0..63]
  {
    float4 a0 = *(const float4*)(bb0 + o0);
    float4 a1 = *(const float4*)(bb0 + o0 + 4);
    const float* Ak = &A[k * 76];
    for (int c = 0; c < 67; ++c) {
      float gv = Ak[c];
      const float* wr = wT0 + c * 64 + o0;
      float4 wa = *(const float4*)wr;
      float4 wb = *(const float4*)(wr + 4);
      a0.x = fmaf(gv, wa.x, a0.x); a0.y = fmaf(gv, wa.y, a0.y);
      a0.z = fmaf(gv, wa.z, a0.z); a0.w = fmaf(gv, wa.w, a0.w);
      a1.x = fmaf(gv, wb.x, a1.x); a1.y = fmaf(gv, wb.y, a1.y);
      a1.z = fmaf(gv, wb.z, a1.z); a1.w = fmaf(gv, wb.w, a1.w);
    }
    float* o = &Bf[k * 76 + o0];
    o[0] = fmaxf(a0.x, 0.f); o[1] = fmaxf(a0.y, 0.f);
    o[2] = fmaxf(a0.z, 0.f); o[3] = fmaxf(a0.w, 0.f);
    o[4] = fmaxf(a1.x, 0.f); o[5] = fmaxf(a1.y, 0.f);
    o[6] = fmaxf(a1.z, 0.f); o[7] = fmaxf(a1.w, 0.f);
  }
  __syncthreads();
  // ---- layer 2: Bf[k][0..63] -> A[k][0..63]
  {
    float4 a0 = *(const float4*)(bb1 + o0);
    float4 a1 = *(const float4*)(bb1 + o0 + 4);
    const float* Bk = &Bf[k * 76];
    for (int c = 0; c < 64; ++c) {
      float gv = Bk[c];
      const float* wr = wT1 + c * 64 + o0;
      float4 wa = *(const float4*)wr;
      float4 wb = *(const float4*)(wr + 4);
      a0.x = fmaf(gv, wa.x, a0.x); a0.y = fmaf(gv, wa.y, a0.y);
      a0.z = fmaf(gv, wa.z, a0.z); a0.w = fmaf(gv, wa.w, a0.w);
      a1.x = fmaf(gv, wb.x, a1.x); a1.y = fmaf(gv, wb.y, a1.y);
      a1.z = fmaf(gv, wb.z, a1.z); a1.w = fmaf(gv, wb.w, a1.w);
    }
    float* o = &A[k * 76 + o0];
    o[0] = fmaxf(a0.x, 0.f); o[1] = fmaxf(a0.y, 0.f);
    o[2] = fmaxf(a0.z, 0.f); o[3] = fmaxf(a0.w, 0.f);
    o[4] = fmaxf(a1.x, 0.f); o[5] = fmaxf(a1.y, 0.f);
    o[6] = fmaxf(a1.z, 0.f); o[7] = fmaxf(a1.w, 0.f);
  }
  __syncthreads();
  // ---- layer 3: A[k][0..63] -> Cf[k][0..127]  (no relu; folded into max)
  {
    const int t0 = j * 16;
    float4 a0 = *(const float4*)(bb2 + t0);
    float4 a1 = *(const float4*)(bb2 + t0 + 4);
    float4 a2 = *(const float4*)(bb2 + t0 + 8);
    float4 a3 = *(const float4*)(bb2 + t0 + 12);
    const float* Ak = &A[k * 76];
    for (int c = 0; c < 64; ++c) {
      float gv = Ak[c];
      const float* wr = wT2 + c * 128 + t0;
      float4 w0v = *(const float4*)wr;
      float4 w1v = *(const float4*)(wr + 4);
      float4 w2v = *(const float4*)(wr + 8);
      float4 w3v = *(const float4*)(wr + 12);
      a0.x = fmaf(gv, w0v.x, a0.x); a0.y = fmaf(gv, w0v.y, a0.y);
      a0.z = fmaf(gv, w0v.z, a0.z); a0.w = fmaf(gv, w0v.w, a0.w);
      a1.x = fmaf(gv, w1v.x, a1.x); a1.y = fmaf(gv, w1v.y, a1.y);
      a1.z = fmaf(gv, w1v.z, a1.z); a1.w = fmaf(gv, w1v.w, a1.w);
      a2.x = fmaf(gv, w2v.x, a2.x); a2.y = fmaf(gv, w2v.y, a2.y);
      a2.z = fmaf(gv, w2v.z, a2.z); a2.w = fmaf(gv, w2v.w, a2.w);
      a3.x = fmaf(gv, w3v.x, a3.x); a3.y = fmaf(gv, w3v.y, a3.y);
      a3.z = fmaf(gv, w3v.z, a3.z); a3.w = fmaf(gv, w3v.w, a3.w);
    }
    float* o = &Cf[k * 132 + t0];
    *(float4*)(o + 0) = a0;
    *(float4*)(o + 4) = a1;
    *(float4*)(o + 8) = a2;
    *(float4*)(o + 12) = a3;
  }
  __syncthreads();
  // ---- max over k, relu, store
  if (tid < 128) {
    float m = Cf[tid];
    for (int kk = 1; kk < 32; ++kk) m = fmaxf(m, Cf[kk * 132 + tid]);
    out[(size_t)(NB * NS * 3) + (size_t)q * 128 + tid] = fmaxf(m, 0.0f);
  }
}

extern "C" void kernel_launch(void* const* d_in, const int* in_sizes, int n_in,
                              void* d_out, int out_size, void* d_ws, size_t ws_size,
                              hipStream_t stream)
{
  (void)in_sizes; (void)n_in; (void)out_size; (void)ws_size;
  const float* xyz  = (const float*)d_in[0];
  const float* feat = (const float*)d_in[1];
  const float* w0 = (const float*)d_in[2];
  const float* b0 = (const float*)d_in[3];
  const float* g0 = (const float*)d_in[4];
  const float* be0 = (const float*)d_in[5];
  const float* m0 = (const float*)d_in[6];
  const float* v0 = (const float*)d_in[7];
  const float* w1 = (const float*)d_in[8];
  const float* b1 = (const float*)d_in[9];
  const float* g1 = (const float*)d_in[10];
  const float* be1 = (const float*)d_in[11];
  const float* m1 = (const float*)d_in[12];
  const float* v1 = (const float*)d_in[13];
  const float* w2 = (const float*)d_in[14];
  const float* b2 = (const float*)d_in[15];
  const float* g2 = (const float*)d_in[16];
  const float* be2 = (const float*)d_in[17];
  const float* m2 = (const float*)d_in[18];
  const float* v2 = (const float*)d_in[19];

  float* ws = (float*)d_ws;
  int* fpsi = (int*)(ws + WS_FPSIDX);
  float* sqx = ws + WS_SQX;
  int* gidx = (int*)(ws + WS_GIDX);
  float* wT0 = ws + WS_WT0; float* bb0 = ws + WS_BB0;
  float* wT1 = ws + WS_WT1; float* bb1 = ws + WS_BB1;
  float* wT2 = ws + WS_WT2; float* bb2 = ws + WS_BB2;
  float* nxyz = (float*)d_out;

  hipLaunchKernelGGL(prep_sqx, dim3((NB * NN + 255) / 256), dim3(256), 0, stream,
                     xyz, sqx);
  hipLaunchKernelGGL(prep_w, dim3(66), dim3(256), 0, stream,
                     w0, b0, g0, be0, m0, v0,
                     w1, b1, g1, be1, m1, v1,
                     w2, b2, g2, be2, m2, v2,
                     wT0, bb0, wT1, bb1, wT2, bb2);
  hipLaunchKernelGGL(fps_kernel, dim3(NB), dim3(1024), 0, stream,
                     xyz, fpsi, nxyz);
  hipLaunchKernelGGL(ballq_kernel, dim3(NB * NS / 4), dim3(256), 0, stream,
                     xyz, sqx, fpsi, gidx);
  hipLaunchKernelGGL(mlp_kernel, dim3(NB * NS), dim3(256), 0, stream,
                     xyz, feat, gidx, nxyz,
                     wT0, bb0, wT1, bb1, wT2, bb2, (float*)d_out);
}

// Round 4
// 3409.060 us; speedup vs baseline: 1.2908x; 1.0012x over previous
//
#include <hip/hip_runtime.h>

#define NB 4
#define NN 8192
#define NS 2048
#define NK 32
#define NCF 64
#define R2 0.04f

// ws layout in float units
#define WS_FPSIDX 0              // int[NB*NS]      = 8192
#define WS_SQX    8192           // float[NB*NN]    = 32768
#define WS_GIDX   40960          // int[NB*NS*NK]   = 262144
#define WS_WT0    303104         // 67*64
#define WS_BB0    307392         // 64
#define WS_WT1    307456         // 64*64
#define WS_BB1    311552         // 64
#define WS_WT2    311616         // 64*128
#define WS_BB2    319808         // 128

template <int CTRL>
__device__ __forceinline__ float dpp_fmax(float x) {
  // bound_ctrl=true: invalid lanes contribute 0.0f; all dist values >= 0 so harmless.
  int t = __builtin_amdgcn_update_dpp(0, __float_as_int(x), CTRL, 0xf, 0xf, true);
  return fmaxf(x, __int_as_float(t));
}

template <int CTRL>
__device__ __forceinline__ void dpp_max64(unsigned& kl, unsigned& kh) {
  // 64-bit max ladder step: shifted-in lanes see key=0 which never wins.
  unsigned nl = (unsigned)__builtin_amdgcn_update_dpp(0, (int)kl, CTRL, 0xf, 0xf, true);
  unsigned nh = (unsigned)__builtin_amdgcn_update_dpp(0, (int)kh, CTRL, 0xf, 0xf, true);
  unsigned long long cur = ((unsigned long long)kh << 32) | kl;
  unsigned long long oth = ((unsigned long long)nh << 32) | nl;
  if (oth > cur) { kl = nl; kh = nh; }   // -> v_cmp_lt_u64 + 2 cndmask
}

// ---------------------------------------------------------------------------
// FPS: one block per batch, 1024 threads, 8 points/thread in registers.
// Exact semantics preserved: dist init 1e10f, far0=0,
// d = ((dx*dx+dy*dy)+dz*dz) with NO fma contraction; dist=min(dist,d);
// argmax with first-index tiebreak.
// Per wave: fmax tree -> 6-step DPP wave max -> ballot index recovery ->
// publish packed key (val<<32 | ~idx) + winner coords via PLAIN LDS stores
// (no atomics -- u64 LDS atomicMax was the round-3 serial bottleneck).
// Post-barrier: all waves reduce the 16 keys in-register via a 4-step 64-bit
// DPP ladder on lanes holding skey[lane&15] (conflict-free broadcast reads).
// One barrier per iteration.
// ---------------------------------------------------------------------------
__global__ __launch_bounds__(1024)
void fps_kernel(const float* __restrict__ xyz, int* __restrict__ fps_idx,
                float* __restrict__ new_xyz)
{
#pragma clang fp contract(off)
  const int b = blockIdx.x;
  const int tid = threadIdx.x;
  const int lane = tid & 63;
  const int wid = tid >> 6;
  const float* __restrict__ P = xyz + (size_t)b * (NN * 3);

  __shared__ unsigned skeyl[2][16];   // double-buffered per-wave packed keys
  __shared__ unsigned skeyh[2][16];
  __shared__ float wslot[2][16][4];   // double-buffered per-wave winner coords

  float px[8], py[8], pz[8], dist[8];
#pragma unroll
  for (int j = 0; j < 8; ++j) {
    int p = tid + j * 1024;
    px[j] = P[p * 3 + 0];
    py[j] = P[p * 3 + 1];
    pz[j] = P[p * 3 + 2];
    dist[j] = 1e10f;
  }
  float cx = P[0], cy = P[1], cz = P[2];   // first center = point 0
  int far = 0;

  for (int k = 0; k < NS; ++k) {
    if (tid == 0) {
      fps_idx[b * NS + k] = far;
      float* o = new_xyz + ((size_t)b * NS + k) * 3;
      o[0] = cx; o[1] = cy; o[2] = cz;
    }
    if (k == NS - 1) break;

    // ---- distance update + thread max tree (exact math, no index tracking)
    float nd[8];
#pragma unroll
    for (int j = 0; j < 8; ++j) {
      float dx = px[j] - cx;
      float dy = py[j] - cy;
      float dz = pz[j] - cz;
      float d = (dx * dx + dy * dy) + dz * dz;   // plain mul/add, l-to-r
      float t = fminf(dist[j], d);
      dist[j] = t;
      nd[j] = t;
    }
    float m0 = fmaxf(nd[0], nd[1]), m1 = fmaxf(nd[2], nd[3]);
    float m2 = fmaxf(nd[4], nd[5]), m3 = fmaxf(nd[6], nd[7]);
    float bv = fmaxf(fmaxf(m0, m1), fmaxf(m2, m3));

    // ---- wave max via DPP ladder (result in lane 63)
    bv = dpp_fmax<0x111>(bv);  // row_shr:1
    bv = dpp_fmax<0x112>(bv);  // row_shr:2
    bv = dpp_fmax<0x114>(bv);  // row_shr:4
    bv = dpp_fmax<0x118>(bv);  // row_shr:8
    bv = dpp_fmax<0x142>(bv);  // row_bcast:15
    bv = dpp_fmax<0x143>(bv);  // row_bcast:31
    unsigned wmaxbits = (unsigned)__builtin_amdgcn_readlane(__float_as_int(bv), 63);
    float wmax = __uint_as_float(wmaxbits);

    // ---- index recovery: global idx = tid + j*1024 -> lexicographic (j, lane)
    int jwin = 0;
    unsigned long long mwin = 0ull;
#pragma unroll
    for (int j = 7; j >= 0; --j) {
      unsigned long long mj = __ballot(dist[j] == wmax);
      if (mj) { jwin = j; mwin = mj; }   // uniform select
    }
    int lanewin = (int)__builtin_ctzll(mwin);
    int widx = wid * 64 + lanewin + jwin * 1024;

    // ---- pull winner coords out of lane `lanewin` (uniform branch on jwin)
    float wxb = 0.f, wyb = 0.f, wzb = 0.f;
#pragma unroll
    for (int j = 0; j < 8; ++j) {
      if (jwin == j) {
        wxb = __int_as_float(__builtin_amdgcn_readlane(__float_as_int(px[j]), lanewin));
        wyb = __int_as_float(__builtin_amdgcn_readlane(__float_as_int(py[j]), lanewin));
        wzb = __int_as_float(__builtin_amdgcn_readlane(__float_as_int(pz[j]), lanewin));
      }
    }
    const int ws = k & 1;
    if (lane == 0) {
      skeyl[ws][wid] = 0xFFFFFFFFu - (unsigned)widx;
      skeyh[ws][wid] = wmaxbits;
      float4 wv; wv.x = wxb; wv.y = wyb; wv.z = wzb; wv.w = 0.f;
      *(float4*)&wslot[ws][wid][0] = wv;
    }
    __syncthreads();

    // ---- cross-wave reduce, replicated per 16-lane row (no atomics)
    unsigned kl = skeyl[ws][lane & 15];   // 16 distinct banks, 4-lane broadcast
    unsigned kh = skeyh[ws][lane & 15];
    dpp_max64<0x111>(kl, kh);  // row_shr:1
    dpp_max64<0x112>(kl, kh);  // row_shr:2
    dpp_max64<0x114>(kl, kh);  // row_shr:4
    dpp_max64<0x118>(kl, kh);  // row_shr:8  -> lane15 of each row has block max
    unsigned kl15 = (unsigned)__builtin_amdgcn_readlane((int)kl, 15);
    far = (int)(0xFFFFFFFFu - kl15);
    int ww = (far & 1023) >> 6;
    cx = wslot[ws][ww][0];
    cy = wslot[ws][ww][1];
    cz = wslot[ws][ww][2];
  }
}

// ---------------------------------------------------------------------------
// sq_x = (x*x + y*y) + z*z, plain ops (matches jnp.sum(xyz**2,-1) reduce order)
// ---------------------------------------------------------------------------
__global__ void prep_sqx(const float* __restrict__ xyz, float* __restrict__ sqx)
{
#pragma clang fp contract(off)
  int t = blockIdx.x * 256 + threadIdx.x;
  if (t < NB * NN) {
    float x = xyz[t * 3 + 0], y = xyz[t * 3 + 1], z = xyz[t * 3 + 2];
    sqx[t] = (x * x + y * y) + z * z;
  }
}

// ---------------------------------------------------------------------------
// Fold BN into weights, transpose to (c,o), remap layer0 channels so that
// c'=0..63 are features (orig 3..66) and c'=64..66 are rel-xyz (orig 0..2).
// ---------------------------------------------------------------------------
__global__ void prep_w(
    const float* __restrict__ w0, const float* __restrict__ b0,
    const float* __restrict__ g0, const float* __restrict__ be0,
    const float* __restrict__ m0, const float* __restrict__ v0,
    const float* __restrict__ w1, const float* __restrict__ b1,
    const float* __restrict__ g1, const float* __restrict__ be1,
    const float* __restrict__ m1, const float* __restrict__ v1,
    const float* __restrict__ w2, const float* __restrict__ b2,
    const float* __restrict__ g2, const float* __restrict__ be2,
    const float* __restrict__ m2, const float* __restrict__ v2,
    float* __restrict__ wT0, float* __restrict__ bb0,
    float* __restrict__ wT1, float* __restrict__ bb1,
    float* __restrict__ wT2, float* __restrict__ bb2)
{
  int t = blockIdx.x * 256 + threadIdx.x;
  if (t < 4288) {
    int c = t >> 6, o = t & 63;
    int oc = (c < 64) ? (c + 3) : (c - 64);
    float sc = g0[o] * rsqrtf(v0[o] + 1e-5f);
    wT0[t] = w0[o * 67 + oc] * sc;
  } else if (t < 4352) {
    int o = t - 4288;
    float sc = g0[o] * rsqrtf(v0[o] + 1e-5f);
    bb0[o] = (b0[o] - m0[o]) * sc + be0[o];
  } else if (t < 8448) {
    int u = t - 4352;
    int c = u >> 6, o = u & 63;
    float sc = g1[o] * rsqrtf(v1[o] + 1e-5f);
    wT1[u] = w1[o * 64 + c] * sc;
  } else if (t < 8512) {
    int o = t - 8448;
    float sc = g1[o] * rsqrtf(v1[o] + 1e-5f);
    bb1[o] = (b1[o] - m1[o]) * sc + be1[o];
  } else if (t < 16704) {
    int u = t - 8512;
    int c = u >> 7, o = u & 127;
    float sc = g2[o] * rsqrtf(v2[o] + 1e-5f);
    wT2[u] = w2[o * 64 + c] * sc;
  } else if (t < 16832) {
    int o = t - 16704;
    float sc = g2[o] * rsqrtf(v2[o] + 1e-5f);
    bb2[o] = (b2[o] - m2[o]) * sc + be2[o];
  }
}

// ---------------------------------------------------------------------------
// Ball query: one wave per query point. sqr = (sq_q + sq_x) - 2*dot with
// dot as Eigen-style fma chain over (x,y,z). First 32 in-ball indices in
// ascending order; pad with the first hit (center itself always in-ball).
// ---------------------------------------------------------------------------
__global__ __launch_bounds__(256)
void ballq_kernel(const float* __restrict__ xyz, const float* __restrict__ sqx,
                  const int* __restrict__ fps_idx, int* __restrict__ gidx)
{
#pragma clang fp contract(off)
  const int lane = threadIdx.x & 63;
  const int q = blockIdx.x * 4 + (threadIdx.x >> 6);
  const int b = q >> 11;
  const int s = q & 2047;
  const float* __restrict__ P = xyz + (size_t)b * (NN * 3);
  const float* __restrict__ SQ = sqx + b * NN;
  const int cidx = fps_idx[b * NS + s];
  const float cx = P[cidx * 3 + 0], cy = P[cidx * 3 + 1], cz = P[cidx * 3 + 2];
  const float csq = SQ[cidx];
  int* __restrict__ g = gidx + (size_t)q * NK;
  int cnt = 0, firstn = 0;
  bool havefirst = false;
  for (int n0 = 0; n0 < NN; n0 += 64) {
    int n = n0 + lane;
    float x = P[n * 3 + 0], y = P[n * 3 + 1], z = P[n * 3 + 2];
    float dot = x * cx;            // first gebp step: fma(a0,b0,0) == rn(a0*b0)
    dot = fmaf(y, cy, dot);
    dot = fmaf(z, cz, dot);
    float sqr = (csq + SQ[n]) - 2.0f * dot;
    bool in_ = (sqr <= R2);
    unsigned long long m = __ballot(in_);
    if (!havefirst && m) { firstn = n0 + __builtin_ctzll(m); havefirst = true; }
    int pos = cnt + __popcll(m & ((1ull << lane) - 1ull));
    if (in_ && pos < NK) g[pos] = n;
    cnt += __popcll(m);
    if (cnt >= NK) break;
  }
  if (cnt < NK && lane < NK - cnt) g[cnt + lane] = firstn;
}

// ---------------------------------------------------------------------------
// Grouped MLP + k-max: one block (256 thr) per query. g staged in LDS,
// weights (BN-folded, (c,o) layout) from global (L2-hot). ReLU of layer 3
// deferred past the max (relu∘max == max∘relu).
// ---------------------------------------------------------------------------
__global__ __launch_bounds__(256)
void mlp_kernel(const float* __restrict__ xyz, const float* __restrict__ feat,
                const int* __restrict__ gidx, const float* __restrict__ nxyz,
                const float* __restrict__ wT0, const float* __restrict__ bb0,
                const float* __restrict__ wT1, const float* __restrict__ bb1,
                const float* __restrict__ wT2, const float* __restrict__ bb2,
                float* __restrict__ out)
{
  const int q = blockIdx.x;
  const int b = q >> 11;
  const int tid = threadIdx.x;
  __shared__ int sg[32];
  __shared__ float A[32 * 76];    // stride 76: conflict-free k-spread
  __shared__ float Bf[32 * 76];
  __shared__ float Cf[32 * 132];
  if (tid < 32) sg[tid] = gidx[(size_t)q * NK + tid];
  __syncthreads();
  const int k = tid >> 3, j = tid & 7;
  {
    const int p = sg[k];
    const float* fp = feat + ((size_t)b * NN + p) * NCF + j * 8;
    float4 f0 = *(const float4*)fp;
    float4 f1 = *(const float4*)(fp + 4);
    float* a = &A[k * 76 + j * 8];
    *(float4*)a = f0;
    *(float4*)(a + 4) = f1;
    if (j == 0) {
      float cx = nxyz[(size_t)q * 3 + 0];
      float cy = nxyz[(size_t)q * 3 + 1];
      float cz = nxyz[(size_t)q * 3 + 2];
      const float* pp = xyz + ((size_t)b * NN + p) * 3;
      A[k * 76 + 64] = pp[0] - cx;
      A[k * 76 + 65] = pp[1] - cy;
      A[k * 76 + 66] = pp[2] - cz;
    }
  }
  __syncthreads();
  const int o0 = j * 8;
  // ---- layer 1: A[k][0..66] -> Bf[k][0..63]
  {
    float4 a0 = *(const float4*)(bb0 + o0);
    float4 a1 = *(const float4*)(bb0 + o0 + 4);
    const float* Ak = &A[k * 76];
    for (int c = 0; c < 67; ++c) {
      float gv = Ak[c];
      const float* wr = wT0 + c * 64 + o0;
      float4 wa = *(const float4*)wr;
      float4 wb = *(const float4*)(wr + 4);
      a0.x = fmaf(gv, wa.x, a0.x); a0.y = fmaf(gv, wa.y, a0.y);
      a0.z = fmaf(gv, wa.z, a0.z); a0.w = fmaf(gv, wa.w, a0.w);
      a1.x = fmaf(gv, wb.x, a1.x); a1.y = fmaf(gv, wb.y, a1.y);
      a1.z = fmaf(gv, wb.z, a1.z); a1.w = fmaf(gv, wb.w, a1.w);
    }
    float* o = &Bf[k * 76 + o0];
    o[0] = fmaxf(a0.x, 0.f); o[1] = fmaxf(a0.y, 0.f);
    o[2] = fmaxf(a0.z, 0.f); o[3] = fmaxf(a0.w, 0.f);
    o[4] = fmaxf(a1.x, 0.f); o[5] = fmaxf(a1.y, 0.f);
    o[6] = fmaxf(a1.z, 0.f); o[7] = fmaxf(a1.w, 0.f);
  }
  __syncthreads();
  // ---- layer 2: Bf[k][0..63] -> A[k][0..63]
  {
    float4 a0 = *(const float4*)(bb1 + o0);
    float4 a1 = *(const float4*)(bb1 + o0 + 4);
    const float* Bk = &Bf[k * 76];
    for (int c = 0; c < 64; ++c) {
      float gv = Bk[c];
      const float* wr = wT1 + c * 64 + o0;
      float4 wa = *(const float4*)wr;
      float4 wb = *(const float4*)(wr + 4);
      a0.x = fmaf(gv, wa.x, a0.x); a0.y = fmaf(gv, wa.y, a0.y);
      a0.z = fmaf(gv, wa.z, a0.z); a0.w = fmaf(gv, wa.w, a0.w);
      a1.x = fmaf(gv, wb.x, a1.x); a1.y = fmaf(gv, wb.y, a1.y);
      a1.z = fmaf(gv, wb.z, a1.z); a1.w = fmaf(gv, wb.w, a1.w);
    }
    float* o = &A[k * 76 + o0];
    o[0] = fmaxf(a0.x, 0.f); o[1] = fmaxf(a0.y, 0.f);
    o[2] = fmaxf(a0.z, 0.f); o[3] = fmaxf(a0.w, 0.f);
    o[4] = fmaxf(a1.x, 0.f); o[5] = fmaxf(a1.y, 0.f);
    o[6] = fmaxf(a1.z, 0.f); o[7] = fmaxf(a1.w, 0.f);
  }
  __syncthreads();
  // ---- layer 3: A[k][0..63] -> Cf[k][0..127]  (no relu; folded into max)
  {
    const int t0 = j * 16;
    float4 a0 = *(const float4*)(bb2 + t0);
    float4 a1 = *(const float4*)(bb2 + t0 + 4);
    float4 a2 = *(const float4*)(bb2 + t0 + 8);
    float4 a3 = *(const float4*)(bb2 + t0 + 12);
    const float* Ak = &A[k * 76];
    for (int c = 0; c < 64; ++c) {
      float gv = Ak[c];
      const float* wr = wT2 + c * 128 + t0;
      float4 w0v = *(const float4*)wr;
      float4 w1v = *(const float4*)(wr + 4);
      float4 w2v = *(const float4*)(wr + 8);
      float4 w3v = *(const float4*)(wr + 12);
      a0.x = fmaf(gv, w0v.x, a0.x); a0.y = fmaf(gv, w0v.y, a0.y);
      a0.z = fmaf(gv, w0v.z, a0.z); a0.w = fmaf(gv, w0v.w, a0.w);
      a1.x = fmaf(gv, w1v.x, a1.x); a1.y = fmaf(gv, w1v.y, a1.y);
      a1.z = fmaf(gv, w1v.z, a1.z); a1.w = fmaf(gv, w1v.w, a1.w);
      a2.x = fmaf(gv, w2v.x, a2.x); a2.y = fmaf(gv, w2v.y, a2.y);
      a2.z = fmaf(gv, w2v.z, a2.z); a2.w = fmaf(gv, w2v.w, a2.w);
      a3.x = fmaf(gv, w3v.x, a3.x); a3.y = fmaf(gv, w3v.y, a3.y);
      a3.z = fmaf(gv, w3v.z, a3.z); a3.w = fmaf(gv, w3v.w, a3.w);
    }
    float* o = &Cf[k * 132 + t0];
    *(float4*)(o + 0) = a0;
    *(float4*)(o + 4) = a1;
    *(float4*)(o + 8) = a2;
    *(float4*)(o + 12) = a3;
  }
  __syncthreads();
  // ---- max over k, relu, store
  if (tid < 128) {
    float m = Cf[tid];
    for (int kk = 1; kk < 32; ++kk) m = fmaxf(m, Cf[kk * 132 + tid]);
    out[(size_t)(NB * NS * 3) + (size_t)q * 128 + tid] = fmaxf(m, 0.0f);
  }
}

extern "C" void kernel_launch(void* const* d_in, const int* in_sizes, int n_in,
                              void* d_out, int out_size, void* d_ws, size_t ws_size,
                              hipStream_t stream)
{
  (void)in_sizes; (void)n_in; (void)out_size; (void)ws_size;
  const float* xyz  = (const float*)d_in[0];
  const float* feat = (const float*)d_in[1];
  const float* w0 = (const float*)d_in[2];
  const float* b0 = (const float*)d_in[3];
  const float* g0 = (const float*)d_in[4];
  const float* be0 = (const float*)d_in[5];
  const float* m0 = (const float*)d_in[6];
  const float* v0 = (const float*)d_in[7];
  const float* w1 = (const float*)d_in[8];
  const float* b1 = (const float*)d_in[9];
  const float* g1 = (const float*)d_in[10];
  const float* be1 = (const float*)d_in[11];
  const float* m1 = (const float*)d_in[12];
  const float* v1 = (const float*)d_in[13];
  const float* w2 = (const float*)d_in[14];
  const float* b2 = (const float*)d_in[15];
  const float* g2 = (const float*)d_in[16];
  const float* be2 = (const float*)d_in[17];
  const float* m2 = (const float*)d_in[18];
  const float* v2 = (const float*)d_in[19];

  float* ws = (float*)d_ws;
  int* fpsi = (int*)(ws + WS_FPSIDX);
  float* sqx = ws + WS_SQX;
  int* gidx = (int*)(ws + WS_GIDX);
  float* wT0 = ws + WS_WT0; float* bb0 = ws + WS_BB0;
  float* wT1 = ws + WS_WT1; float* bb1 = ws + WS_BB1;
  float* wT2 = ws + WS_WT2; float* bb2 = ws + WS_BB2;
  float* nxyz = (float*)d_out;

  hipLaunchKernelGGL(prep_sqx, dim3((NB * NN + 255) / 256), dim3(256), 0, stream,
                     xyz, sqx);
  hipLaunchKernelGGL(prep_w, dim3(66), dim3(256), 0, stream,
                     w0, b0, g0, be0, m0, v0,
                     w1, b1, g1, be1, m1, v1,
                     w2, b2, g2, be2, m2, v2,
                     wT0, bb0, wT1, bb1, wT2, bb2);
  hipLaunchKernelGGL(fps_kernel, dim3(NB), dim3(1024), 0, stream,
                     xyz, fpsi, nxyz);
  hipLaunchKernelGGL(ballq_kernel, dim3(NB * NS / 4), dim3(256), 0, stream,
                     xyz, sqx, fpsi, gidx);
  hipLaunchKernelGGL(mlp_kernel, dim3(NB * NS), dim3(256), 0, stream,
                     xyz, feat, gidx, nxyz,
                     wT0, bb0, wT1, bb1, wT2, bb2, (float*)d_out);
}